// Round 10
// baseline (191.310 us; speedup 1.0000x reference)
//
#include <hip/hip_runtime.h>
#include <math.h>

static constexpr int kM = 80;
static constexpr int kT = 4000;
static constexpr int kB = 64;
static constexpr int kLow = kM / 3;                 // 26
static constexpr int kHighStart = 2 * kM / 3;       // 53
static constexpr int kHighCount = kM - kHighStart;  // 27
static constexpr int kTrunc = 12;                   // A_ns^12 = 0.95^192 ~ 5e-5
static constexpr int kGroups = 5;                   // 5 groups x 16 channels
static constexpr int kGQ = 4;                       // planes: slog,ssum,slow,shigh
static constexpr size_t kGateFloats = (size_t)kB * kT;              // 256000
static constexpr size_t kPartFloats = (size_t)kB * kGroups * kGQ * kT; // 5.12M
#define EPSF 1e-6f
#define LOG2E 1.4426950408889634f

typedef float vfloat4 __attribute__((ext_vector_type(4)));
typedef float vfloat2 __attribute__((ext_vector_type(2)));

__device__ __forceinline__ float hw_exp2(float x) { return __builtin_amdgcn_exp2f(x); }
__device__ __forceinline__ float hw_log2(float x) { return __builtin_amdgcn_logf(x); }

__device__ __forceinline__ float fast_sigmoid(float x) {
    return __builtin_amdgcn_rcpf(1.0f + hw_exp2(-x * LOG2E));
}

// ---------------- Stage 1: row-streaming partial reduction ------------------
// The cross-channel reduction read ROW-WISE: block = (b, 16-channel group,
// quarter-row slice). Per channel iteration the block reads a 4 KB
// SEQUENTIAL burst (fill-like DRAM pattern) instead of gate's 0.5-1 KB
// strips at 16 KB stride (~page-miss per strip, ~2.2 TB/s effective).
// Accumulate 4 quantities x float4 in registers; no LDS, no barriers.
// grid (4, 320) = 1280 blocks -> 5 blocks/CU, 20 waves/CU.
__global__ __launch_bounds__(256) void partial_kernel(
    const float* __restrict__ mel,
    float* __restrict__ part)
{
    const int tid = threadIdx.x;
    const int tq  = blockIdx.x;                 // quarter-row slice 0..3
    const int bg  = blockIdx.y;                 // b*5 + g, 0..319
    const int b   = bg / kGroups;
    const int g   = bg - b * kGroups;
    const int t0  = tq * (kT / 4) + tid * 4;    // 16B-aligned (1000*4B = 16*250)
    const bool valid = (tid < 250);             // 250 float4 per slice

    const int m0 = g * 16;
    vfloat4 slog = {0.f,0.f,0.f,0.f}, ssum = {0.f,0.f,0.f,0.f};
    vfloat4 slow = {0.f,0.f,0.f,0.f}, shigh = {0.f,0.f,0.f,0.f};

    if (valid) {
        const float* base = mel + ((size_t)b * kM + m0) * kT + t0;
        #pragma unroll
        for (int j = 0; j < 16; ++j) {
            const int m = m0 + j;               // wave-uniform
            const vfloat4 v = *reinterpret_cast<const vfloat4*>(base + (size_t)j * kT);
            vfloat4 lg;
            lg.x = hw_log2(v.x + 1e-8f); lg.y = hw_log2(v.y + 1e-8f);
            lg.z = hw_log2(v.z + 1e-8f); lg.w = hw_log2(v.w + 1e-8f);
            slog += lg;
            ssum += v;
            if (m < kLow)        slow  += v;    // uniform branch (scc)
            if (m >= kHighStart) shigh += v;
        }
        float* pb = part + ((size_t)bg * kGQ) * kT + t0;
        *reinterpret_cast<vfloat4*>(pb)          = slog;
        *reinterpret_cast<vfloat4*>(pb +   kT)   = ssum;
        *reinterpret_cast<vfloat4*>(pb + 2*kT)   = slow;
        *reinterpret_cast<vfloat4*>(pb + 3*kT)   = shigh;
    }
}

// ---------------- Stage 2: finalize gate from partials ----------------------
// Sums the 5 group-partials (20.5 MB, L2/L3-hot from stage 1) and applies
// the gate math. grid (4, 64) = 256 blocks; tiny kernel (~4 us).
__global__ __launch_bounds__(256) void gate_finalize_kernel(
    const float* __restrict__ part,
    const float* __restrict__ gate_temp,
    float* __restrict__ gate)
{
    const int tid = threadIdx.x;
    const int tq  = blockIdx.x;
    const int b   = blockIdx.y;
    const int t0  = tq * (kT / 4) + tid * 4;
    if (tid >= 250) return;

    vfloat4 tlog = {0.f,0.f,0.f,0.f}, tsum = {0.f,0.f,0.f,0.f};
    vfloat4 tlow = {0.f,0.f,0.f,0.f}, thigh = {0.f,0.f,0.f,0.f};
    #pragma unroll
    for (int g = 0; g < kGroups; ++g) {
        const float* pb = part + ((size_t)(b * kGroups + g) * kGQ) * kT + t0;
        tlog  += *reinterpret_cast<const vfloat4*>(pb);
        tsum  += *reinterpret_cast<const vfloat4*>(pb +   kT);
        tlow  += *reinterpret_cast<const vfloat4*>(pb + 2*kT);
        thigh += *reinterpret_cast<const vfloat4*>(pb + 3*kT);
    }

    const float gt = gate_temp[0];
    vfloat4 o;
    #pragma unroll
    for (int q = 0; q < 4; ++q) {
        const float sl = tlog[q];       // ext_vector subscript (not &v.x !)
        const float ss = tsum[q];
        const float lo = tlow[q];
        const float hi = thigh[q];
        const float geo   = hw_exp2(sl * (1.0f / kM));
        const float arith = ss * (1.0f / kM) + 1e-8f;
        float sf = geo * __builtin_amdgcn_rcpf(arith);
        sf = fminf(fmaxf(sf, 0.0f), 1.0f);
        const float low  = lo * (1.0f / kLow);
        const float high = hi * (1.0f / kHighCount);
        float tilt = low * __builtin_amdgcn_rcpf(low + high + 1e-8f);
        tilt = fminf(fmaxf(tilt, 0.0f), 1.0f);
        const float sfa = sf + (1.0f - sf) * fmaxf(tilt - 0.6f, 0.0f);
        o[q] = fast_sigmoid(gt * (sfa - 0.5f));
    }
    *reinterpret_cast<vfloat4*>(gate + (size_t)b * kT + t0) = o;
}

// ---------------- Fallback gate (the 180.1us config) — used if ws too small -
__global__ __launch_bounds__(256) void gate_kernel(
    const float* __restrict__ mel,
    const float* __restrict__ gate_temp,
    float* __restrict__ gate)
{
    const int tid = threadIdx.x;
    const int c   = tid & 127;
    const int h   = tid >> 7;
    const int b   = blockIdx.y;
    const int col = blockIdx.x * 128 + c;
    const bool valid = (col < kT);

    const float* base = mel + (size_t)b * kM * kT + col;

    float slog = 0.f, ssum = 0.f, sband = 0.f;
    if (valid) {
        if (h == 0) {
            #pragma unroll 20
            for (int m = 0; m < 40; ++m) {
                const float v = base[(size_t)m * kT];
                slog += hw_log2(v + 1e-8f);
                ssum += v;
                if (m < kLow) sband += v;
            }
        } else {
            #pragma unroll 20
            for (int m = 40; m < 80; ++m) {
                const float v = base[(size_t)m * kT];
                slog += hw_log2(v + 1e-8f);
                ssum += v;
                if (m >= kHighStart) sband += v;
            }
        }
    }

    __shared__ float p1[3][128];
    if (h == 1) {
        p1[0][c] = slog; p1[1][c] = ssum; p1[2][c] = sband;
    }
    __syncthreads();

    if (h == 0 && valid) {
        const float tlog  = slog + p1[0][c];
        const float tsum  = ssum + p1[1][c];
        const float thigh = p1[2][c];
        const float tlow  = sband;

        const float gt = gate_temp[0];
        const float geo   = hw_exp2(tlog * (1.0f / kM));
        const float arith = tsum * (1.0f / kM) + 1e-8f;
        float sf = geo * __builtin_amdgcn_rcpf(arith);
        sf = fminf(fmaxf(sf, 0.0f), 1.0f);
        const float low  = tlow  * (1.0f / kLow);
        const float high = thigh * (1.0f / kHighCount);
        float tilt = low * __builtin_amdgcn_rcpf(low + high + 1e-8f);
        tilt = fminf(fmaxf(tilt, 0.0f), 1.0f);
        const float sfa = sf + (1.0f - sf) * fmaxf(tilt - 0.6f, 0.0f);
        gate[(size_t)b * kT + col] = fast_sigmoid(gt * (sfa - 0.5f));
    }
}

// ---------------- Kernel B: dual PCEN — B-compose carry (180.1us version) ---
// Block per (b,m) row. Thread i owns 16 contiguous elements. Carry via the
// data-independent chunk transform (A = a^16 per-row constant):
//   carry_i = sum_{k<12} A^k B_{i-1-k} (+ A^i x0 exactly for i<=12).
__global__ __launch_bounds__(256) void pcen_kernel(
    const float* __restrict__ mel,
    const float* __restrict__ ls_ns, const float* __restrict__ la_ns,
    const float* __restrict__ ld_ns, const float* __restrict__ lr_ns,
    const float* __restrict__ ls_st, const float* __restrict__ la_st,
    const float* __restrict__ ld_st, const float* __restrict__ lr_st,
    const float* __restrict__ gate,
    float* __restrict__ out)
{
    const int m = blockIdx.x;
    const int b = blockIdx.y;

    const float s_ns     = fminf(fmaxf(fast_sigmoid(ls_ns[m]), 0.05f), 0.3f);
    const float alpha_ns = fminf(fmaxf(fast_sigmoid(la_ns[m]), 0.9f), 0.999f);
    const float delta_ns = fminf(fmaxf(hw_exp2(ld_ns[m] * LOG2E), 0.5f), 5.0f);
    const float r_ns     = fminf(fmaxf(fast_sigmoid(lr_ns[m]), 0.05f), 0.25f);
    const float s_st     = fminf(fmaxf(fast_sigmoid(ls_st[m]), 0.05f), 0.3f);
    const float alpha_st = fminf(fmaxf(fast_sigmoid(la_st[m]), 0.9f), 0.999f);
    const float delta_st = fminf(fmaxf(hw_exp2(ld_st[m] * LOG2E), 0.001f), 0.1f);
    const float r_st     = fminf(fmaxf(fast_sigmoid(lr_st[m]), 0.05f), 0.25f);
    const float dr_ns = hw_exp2(r_ns * hw_log2(delta_ns));   // delta^r
    const float dr_st = hw_exp2(r_st * hw_log2(delta_st));

    const vfloat2 a2 = {1.0f - s_ns, 1.0f - s_st};
    const vfloat2 s2 = {s_ns, s_st};
    const vfloat2 d2 = {delta_ns, delta_st};
    const float man = -alpha_ns, mas = -alpha_st;

    const size_t rowoff = ((size_t)b * kM + m) * kT;
    const float* row = mel + rowoff;

    const int i  = threadIdx.x;         // chunk index
    const int t0 = i * 16;
    const bool valid = (t0 < kT);       // tids 250..255 idle

    float x[16];
    float gv[16];
    if (valid) {
        const float4* p = reinterpret_cast<const float4*>(row + t0);
        #pragma unroll
        for (int q = 0; q < 4; ++q) {
            const float4 v = p[q];
            x[4*q+0] = v.x; x[4*q+1] = v.y; x[4*q+2] = v.z; x[4*q+3] = v.w;
        }
        const float4* gp = reinterpret_cast<const float4*>(gate + (size_t)b * kT + t0);
        #pragma unroll
        for (int q = 0; q < 4; ++q) {
            const float4 v = gp[q];
            gv[4*q+0] = v.x; gv[4*q+1] = v.y; gv[4*q+2] = v.z; gv[4*q+3] = v.w;
        }
    } else {
        #pragma unroll
        for (int k = 0; k < 16; ++k) { x[k] = 0.0f; gv[k] = 0.0f; }
    }

    __shared__ float sv0;
    if (i == 0) sv0 = x[0];

    // local chunk offset B_i (16 serial pk_fma); transform is v -> A*v + B_i
    vfloat2 Bv = {0.0f, 0.0f};
    #pragma unroll
    for (int k = 0; k < 16; ++k) {
        Bv = a2 * Bv + s2 * x[k];       // v_pk_fma_f32
    }
    const vfloat2 p2  = a2 * a2;
    const vfloat2 p4  = p2 * p2;
    const vfloat2 p8  = p4 * p4;
    const vfloat2 A2  = p8 * p8;        // a^16 (data-independent)

    __shared__ vfloat2 Btab[256];
    Btab[i] = Bv;
    __syncthreads();

    // carry: sm = sum_{k=0}^{11} A^k B_{i-1-k}  (+ A^i x0 exactly if i<=12)
    vfloat2 sm = {0.0f, 0.0f};
    vfloat2 pw = {1.0f, 1.0f};
    #pragma unroll
    for (int k = 0; k < kTrunc; ++k) {
        const vfloat2 Bk = Btab[(i - 1 - k) & 255];
        if (k < i) {
            sm = pw * Bk + sm;
            pw = pw * A2;
        }
    }
    if (i <= kTrunc) {
        const float x0 = sv0;
        const vfloat2 x02 = {x0, x0};
        sm = pw * x02 + sm;             // pw = A^i here; exact init term
    }

    // ---- streaming main pass over the owned 16 elements ----
    if (valid) {
        float4* op = reinterpret_cast<float4*>(out + rowoff + t0);
        #pragma unroll
        for (int q = 0; q < 4; ++q) {
            float4 v;
            #pragma unroll
            for (int j = 0; j < 4; ++j) {
                const int k = 4*q + j;
                const float xv = x[k];
                sm = a2 * sm + s2 * xv;            // v_pk_fma_f32
                vfloat2 g2;
                g2.x = hw_exp2(man * hw_log2(sm.x + EPSF));
                g2.y = hw_exp2(mas * hw_log2(sm.y + EPSF));
                const vfloat2 u2 = g2 * xv + d2;   // v_pk_fma_f32
                const float on = hw_exp2(r_ns * hw_log2(u2.x)) - dr_ns;
                const float os = hw_exp2(r_st * hw_log2(u2.y)) - dr_st;
                (&v.x)[j] = fmaf(gv[k], os - on, on);   // float4 struct: ok
            }
            op[q] = v;                              // plain cached stores
        }
    }
}

extern "C" void kernel_launch(void* const* d_in, const int* in_sizes, int n_in,
                              void* d_out, int out_size, void* d_ws, size_t ws_size,
                              hipStream_t stream)
{
    const float* mel       = (const float*)d_in[0];
    const float* ls_ns     = (const float*)d_in[1];
    const float* la_ns     = (const float*)d_in[2];
    const float* ld_ns     = (const float*)d_in[3];
    const float* lr_ns     = (const float*)d_in[4];
    const float* ls_st     = (const float*)d_in[5];
    const float* la_st     = (const float*)d_in[6];
    const float* ld_st     = (const float*)d_in[7];
    const float* lr_st     = (const float*)d_in[8];
    const float* gate_temp = (const float*)d_in[9];
    float* out  = (float*)d_out;
    float* gate = (float*)d_ws;   // gate: 1.02 MB at ws[0]

    const size_t need = (kGateFloats + kPartFloats) * sizeof(float);
    if (ws_size >= need) {
        float* part = gate + kGateFloats;   // 20.5 MB partials
        partial_kernel<<<dim3(4, kB * kGroups), 256, 0, stream>>>(mel, part);
        gate_finalize_kernel<<<dim3(4, kB), 256, 0, stream>>>(part, gate_temp, gate);
    } else {
        dim3 gA((kT + 127) / 128, kB);      // fallback: 180.1us gate
        gate_kernel<<<gA, 256, 0, stream>>>(mel, gate_temp, gate);
    }

    dim3 gB(kM, kB);                        // 5120 blocks, one (b,m) row each
    pcen_kernel<<<gB, 256, 0, stream>>>(mel, ls_ns, la_ns, ld_ns, lr_ns,
                                        ls_st, la_st, ld_st, lr_st, gate, out);
}

// Round 11
// 181.237 us; speedup vs baseline: 1.0556x; 1.0556x over previous
//
#include <hip/hip_runtime.h>
#include <math.h>

static constexpr int kM = 80;
static constexpr int kT = 4000;
static constexpr int kB = 64;
static constexpr int kLow = kM / 3;                 // 26
static constexpr int kHighStart = 2 * kM / 3;       // 53
static constexpr int kHighCount = kM - kHighStart;  // 27
static constexpr int kTrunc = 12;                   // A_ns^12 = 0.95^192 ~ 5e-5
#define EPSF 1e-6f
#define LOG2E 1.4426950408889634f

typedef float vfloat4 __attribute__((ext_vector_type(4)));
typedef float vfloat2 __attribute__((ext_vector_type(2)));

__device__ __forceinline__ float hw_exp2(float x) { return __builtin_amdgcn_exp2f(x); }
__device__ __forceinline__ float hw_log2(float x) { return __builtin_amdgcn_logf(x); }

__device__ __forceinline__ float fast_sigmoid(float x) {
    return __builtin_amdgcn_rcpf(1.0f + hw_exp2(-x * LOG2E));
}

// ---------------- Kernel A: gate[b,t] — BATCHED-load quarter-split ----------
// Theory: all prior gates ran ~2.2-2.5 TB/s because loads were interleaved
// with log2 compute -> compiler pipelines only ~2-4 loads deep -> BW =
// bytes-in-flight/latency ~ 16 waves x 4 x 8-16B / 375ns ~ 2 TB/s.
// Fix: phase A issues ALL 20 float4 loads into registers back-to-back
// (20 KB in flight per wave, 320 KB/CU), phase B does the math.
// Wave w owns channels [20w, 20w+20); lane owns one float4 column.
// grid (16, 64) = 1024 blocks, 4 blocks/CU, 16 waves/CU.
__global__ __launch_bounds__(256, 4) void gate_kernel(
    const float* __restrict__ mel,
    const float* __restrict__ gate_temp,
    float* __restrict__ gate)
{
    const int lane = threadIdx.x & 63;
    const int wid  = threadIdx.x >> 6;
    const int b    = blockIdx.y;
    const int t0   = blockIdx.x * 256 + lane * 4;
    const bool valid = (t0 < kT);

    const float* base = mel + (size_t)b * kM * kT + t0;
    const int m0 = wid * 20;

    vfloat4 slog = {0.f,0.f,0.f,0.f}, ssum = {0.f,0.f,0.f,0.f};
    vfloat4 slow = {0.f,0.f,0.f,0.f}, shigh = {0.f,0.f,0.f,0.f};

    if (valid) {
        // ---- phase A: issue all 20 loads, no dependent compute between ----
        vfloat4 v[20];
        #pragma unroll
        for (int j = 0; j < 20; ++j) {
            v[j] = *reinterpret_cast<const vfloat4*>(base + (size_t)(m0 + j) * kT);
        }
        // ---- phase B: reduce ----
        #pragma unroll
        for (int j = 0; j < 20; ++j) {
            const int m = m0 + j;
            vfloat4 lg;
            lg.x = hw_log2(v[j].x + 1e-8f); lg.y = hw_log2(v[j].y + 1e-8f);
            lg.z = hw_log2(v[j].z + 1e-8f); lg.w = hw_log2(v[j].w + 1e-8f);
            slog += lg;
            ssum += v[j];
            if (m < kLow)        slow  += v[j];   // compile-time after unroll
            if (m >= kHighStart) shigh += v[j];
        }
    }

    __shared__ vfloat4 sh[4][4][64];   // [wid][qty][lane] = 16 KB
    sh[wid][0][lane] = slog;
    sh[wid][1][lane] = ssum;
    sh[wid][2][lane] = slow;
    sh[wid][3][lane] = shigh;
    __syncthreads();

    if (wid == 0 && valid) {
        slog  = sh[0][0][lane] + sh[1][0][lane] + sh[2][0][lane] + sh[3][0][lane];
        ssum  = sh[0][1][lane] + sh[1][1][lane] + sh[2][1][lane] + sh[3][1][lane];
        slow  = sh[0][2][lane] + sh[1][2][lane] + sh[2][2][lane] + sh[3][2][lane];
        shigh = sh[0][3][lane] + sh[1][3][lane] + sh[2][3][lane] + sh[3][3][lane];

        const float gt = gate_temp[0];
        vfloat4 o;
        #pragma unroll
        for (int q = 0; q < 4; ++q) {
            const float sl = slog[q];
            const float ss = ssum[q];
            const float lo = slow[q];
            const float hi = shigh[q];
            const float geo   = hw_exp2(sl * (1.0f / kM));
            const float arith = ss * (1.0f / kM) + 1e-8f;
            float sf = geo * __builtin_amdgcn_rcpf(arith);
            sf = fminf(fmaxf(sf, 0.0f), 1.0f);
            const float low  = lo * (1.0f / kLow);
            const float high = hi * (1.0f / kHighCount);
            float tilt = low * __builtin_amdgcn_rcpf(low + high + 1e-8f);
            tilt = fminf(fmaxf(tilt, 0.0f), 1.0f);
            const float sfa = sf + (1.0f - sf) * fmaxf(tilt - 0.6f, 0.0f);
            o[q] = fast_sigmoid(gt * (sfa - 0.5f));
        }
        *reinterpret_cast<vfloat4*>(gate + (size_t)b * kT + t0) = o;
    }
}

// ---------------- Kernel B: dual PCEN — B-compose carry (180.1us version) ---
// Block per (b,m) row. Thread i owns 16 contiguous elements. Carry via the
// data-independent chunk transform (A = a^16 per-row constant):
//   carry_i = sum_{k<12} A^k B_{i-1-k} (+ A^i x0 exactly for i<=12).
__global__ __launch_bounds__(256) void pcen_kernel(
    const float* __restrict__ mel,
    const float* __restrict__ ls_ns, const float* __restrict__ la_ns,
    const float* __restrict__ ld_ns, const float* __restrict__ lr_ns,
    const float* __restrict__ ls_st, const float* __restrict__ la_st,
    const float* __restrict__ ld_st, const float* __restrict__ lr_st,
    const float* __restrict__ gate,
    float* __restrict__ out)
{
    const int m = blockIdx.x;
    const int b = blockIdx.y;

    const float s_ns     = fminf(fmaxf(fast_sigmoid(ls_ns[m]), 0.05f), 0.3f);
    const float alpha_ns = fminf(fmaxf(fast_sigmoid(la_ns[m]), 0.9f), 0.999f);
    const float delta_ns = fminf(fmaxf(hw_exp2(ld_ns[m] * LOG2E), 0.5f), 5.0f);
    const float r_ns     = fminf(fmaxf(fast_sigmoid(lr_ns[m]), 0.05f), 0.25f);
    const float s_st     = fminf(fmaxf(fast_sigmoid(ls_st[m]), 0.05f), 0.3f);
    const float alpha_st = fminf(fmaxf(fast_sigmoid(la_st[m]), 0.9f), 0.999f);
    const float delta_st = fminf(fmaxf(hw_exp2(ld_st[m] * LOG2E), 0.001f), 0.1f);
    const float r_st     = fminf(fmaxf(fast_sigmoid(lr_st[m]), 0.05f), 0.25f);
    const float dr_ns = hw_exp2(r_ns * hw_log2(delta_ns));   // delta^r
    const float dr_st = hw_exp2(r_st * hw_log2(delta_st));

    const vfloat2 a2 = {1.0f - s_ns, 1.0f - s_st};
    const vfloat2 s2 = {s_ns, s_st};
    const vfloat2 d2 = {delta_ns, delta_st};
    const float man = -alpha_ns, mas = -alpha_st;

    const size_t rowoff = ((size_t)b * kM + m) * kT;
    const float* row = mel + rowoff;

    const int i  = threadIdx.x;         // chunk index
    const int t0 = i * 16;
    const bool valid = (t0 < kT);       // tids 250..255 idle

    float x[16];
    float gv[16];
    if (valid) {
        const float4* p = reinterpret_cast<const float4*>(row + t0);
        #pragma unroll
        for (int q = 0; q < 4; ++q) {
            const float4 v = p[q];
            x[4*q+0] = v.x; x[4*q+1] = v.y; x[4*q+2] = v.z; x[4*q+3] = v.w;
        }
        const float4* gp = reinterpret_cast<const float4*>(gate + (size_t)b * kT + t0);
        #pragma unroll
        for (int q = 0; q < 4; ++q) {
            const float4 v = gp[q];
            gv[4*q+0] = v.x; gv[4*q+1] = v.y; gv[4*q+2] = v.z; gv[4*q+3] = v.w;
        }
    } else {
        #pragma unroll
        for (int k = 0; k < 16; ++k) { x[k] = 0.0f; gv[k] = 0.0f; }
    }

    __shared__ float sv0;
    if (i == 0) sv0 = x[0];

    // local chunk offset B_i (16 serial pk_fma); transform is v -> A*v + B_i
    vfloat2 Bv = {0.0f, 0.0f};
    #pragma unroll
    for (int k = 0; k < 16; ++k) {
        Bv = a2 * Bv + s2 * x[k];       // v_pk_fma_f32
    }
    const vfloat2 p2  = a2 * a2;
    const vfloat2 p4  = p2 * p2;
    const vfloat2 p8  = p4 * p4;
    const vfloat2 A2  = p8 * p8;        // a^16 (data-independent)

    __shared__ vfloat2 Btab[256];
    Btab[i] = Bv;
    __syncthreads();

    // carry: sm = sum_{k=0}^{11} A^k B_{i-1-k}  (+ A^i x0 exactly if i<=12)
    vfloat2 sm = {0.0f, 0.0f};
    vfloat2 pw = {1.0f, 1.0f};
    #pragma unroll
    for (int k = 0; k < kTrunc; ++k) {
        const vfloat2 Bk = Btab[(i - 1 - k) & 255];
        if (k < i) {
            sm = pw * Bk + sm;
            pw = pw * A2;
        }
    }
    if (i <= kTrunc) {
        const float x0 = sv0;
        const vfloat2 x02 = {x0, x0};
        sm = pw * x02 + sm;             // pw = A^i here; exact init term
    }

    // ---- streaming main pass over the owned 16 elements ----
    if (valid) {
        float4* op = reinterpret_cast<float4*>(out + rowoff + t0);
        #pragma unroll
        for (int q = 0; q < 4; ++q) {
            float4 v;
            #pragma unroll
            for (int j = 0; j < 4; ++j) {
                const int k = 4*q + j;
                const float xv = x[k];
                sm = a2 * sm + s2 * xv;            // v_pk_fma_f32
                vfloat2 g2;
                g2.x = hw_exp2(man * hw_log2(sm.x + EPSF));
                g2.y = hw_exp2(mas * hw_log2(sm.y + EPSF));
                const vfloat2 u2 = g2 * xv + d2;   // v_pk_fma_f32
                const float on = hw_exp2(r_ns * hw_log2(u2.x)) - dr_ns;
                const float os = hw_exp2(r_st * hw_log2(u2.y)) - dr_st;
                (&v.x)[j] = fmaf(gv[k], os - on, on);   // float4 struct: ok
            }
            op[q] = v;                              // plain cached stores
        }
    }
}

extern "C" void kernel_launch(void* const* d_in, const int* in_sizes, int n_in,
                              void* d_out, int out_size, void* d_ws, size_t ws_size,
                              hipStream_t stream)
{
    const float* mel       = (const float*)d_in[0];
    const float* ls_ns     = (const float*)d_in[1];
    const float* la_ns     = (const float*)d_in[2];
    const float* ld_ns     = (const float*)d_in[3];
    const float* lr_ns     = (const float*)d_in[4];
    const float* ls_st     = (const float*)d_in[5];
    const float* la_st     = (const float*)d_in[6];
    const float* ld_st     = (const float*)d_in[7];
    const float* lr_st     = (const float*)d_in[8];
    const float* gate_temp = (const float*)d_in[9];
    float* out  = (float*)d_out;
    float* gate = (float*)d_ws;   // kB*kT floats = 1.02 MB scratch

    dim3 gA(16, kB);                     // 1024 blocks, 16 waves/CU
    gate_kernel<<<gA, 256, 0, stream>>>(mel, gate_temp, gate);

    dim3 gB(kM, kB);                     // 5120 blocks, one (b,m) row each
    pcen_kernel<<<gB, 256, 0, stream>>>(mel, ls_ns, la_ns, ld_ns, lr_ns,
                                        ls_st, la_st, ld_st, lr_st, gate, out);
}